// Round 2
// baseline (794.294 us; speedup 1.0000x reference)
//
#include <hip/hip_runtime.h>
#include <hip/hip_bf16.h>
#include <math.h>

#define B_ 8
#define Q_ 150
#define QP_ 160     // padded Q for MFMA (10 m-tiles of 16)
#define C_ 134
#define T_ 32
#define H_ 160
#define W_ 160
#define P_ 12544
#define HW_ (H_ * W_)

// phase 1 (pm sampling)
#define QTILE 10
#define NQT 15      // Q_/QTILE
#define CHUNK 256
#define NCHUNK 49   // P_/CHUNK
// phase 2 (tm sampling)
#define TTILE 8
// phase 3 (GEMM)
#define SEG_ 56
#define KSEG 224    // P_/SEG_
#define KITER 7     // KSEG/32

typedef __attribute__((ext_vector_type(8))) short short8;
typedef __attribute__((ext_vector_type(4))) float floatx4;

struct Samp {
  int i00, i01, i10, i11;
  float w00, w01, w10, w11;
};

__device__ __forceinline__ Samp make_samp(float cx, float cy) {
  float x = cx * (float)W_ - 0.5f;
  float y = cy * (float)H_ - 0.5f;
  float x0f = floorf(x), y0f = floorf(y);
  float tx = x - x0f, ty = y - y0f;
  int x0 = (int)x0f, y0 = (int)y0f;
  int x1 = x0 + 1, y1 = y0 + 1;
  bool vx0 = (x0 >= 0) && (x0 < W_);
  bool vx1 = (x1 >= 0) && (x1 < W_);
  bool vy0 = (y0 >= 0) && (y0 < H_);
  bool vy1 = (y1 >= 0) && (y1 < H_);
  int cx0 = min(max(x0, 0), W_ - 1), cx1 = min(max(x1, 0), W_ - 1);
  int cy0 = min(max(y0, 0), H_ - 1), cy1 = min(max(y1, 0), H_ - 1);
  Samp s;
  s.i00 = cy0 * W_ + cx0;
  s.i01 = cy0 * W_ + cx1;
  s.i10 = cy1 * W_ + cx0;
  s.i11 = cy1 * W_ + cx1;
  float w00 = (1.f - tx) * (1.f - ty);
  float w01 = tx * (1.f - ty);
  float w10 = (1.f - tx) * ty;
  float w11 = tx * ty;
  s.w00 = (vx0 && vy0) ? w00 : 0.f;
  s.w01 = (vx1 && vy0) ? w01 : 0.f;
  s.w10 = (vx0 && vy1) ? w10 : 0.f;
  s.w11 = (vx1 && vy1) ? w11 : 0.f;
  return s;
}

__device__ __forceinline__ float waveSum(float v) {
#pragma unroll
  for (int m = 32; m >= 1; m >>= 1) v += __shfl_xor(v, m, 64);
  return v;
}
__device__ __forceinline__ float waveMax(float v) {
#pragma unroll
  for (int m = 32; m >= 1; m >>= 1) v = fmaxf(v, __shfl_xor(v, m, 64));
  return v;
}

__device__ __forceinline__ unsigned short f2bf(float x) {
  union { __hip_bfloat16 h; unsigned short u; } cv;
  cv.h = __float2bfloat16(x);
  return cv.u;
}
__device__ __forceinline__ float bf2f(unsigned short u) {
  return __uint_as_float(((unsigned int)u) << 16);
}

// ---------------- phase 1: sample pm -> bf16 pmh[B][QP_][P], S_sp/S_sig atomics
__launch_bounds__(256) __global__
void pm_kernel(const float* __restrict__ masks_q,
               const float* __restrict__ coords,
               unsigned short* __restrict__ pmh,
               float* __restrict__ S_sp, float* __restrict__ S_sig) {
  const int b = blockIdx.z;
  const int p = blockIdx.x * CHUNK + threadIdx.x;
  const float2* c2 = (const float2*)coords;
  float2 cc = c2[(size_t)b * P_ + p];
  Samp s = make_samp(cc.x, cc.y);
#pragma unroll
  for (int g = 0; g < QTILE; ++g) {
    int q = blockIdx.y * QTILE + g;
    const float* img = masks_q + ((size_t)b * Q_ + q) * HW_;
    float pm = s.w00 * img[s.i00] + s.w01 * img[s.i01] +
               s.w10 * img[s.i10] + s.w11 * img[s.i11];
    float e = __expf(-fabsf(pm));
    float sp = fmaxf(pm, 0.f) + __logf(1.f + e);
    float r = __builtin_amdgcn_rcpf(1.f + e);
    float sg = (pm >= 0.f) ? r : e * r;
    pmh[((size_t)b * QP_ + q) * P_ + p] = f2bf(pm);
    float wsp = waveSum(sp);
    float wsg = waveSum(sg);
    if ((threadIdx.x & 63) == 0) {
      atomicAdd(&S_sp[b * Q_ + q], wsp);
      atomicAdd(&S_sig[b * Q_ + q], wsg);
    }
  }
}

// ---------------- phase 2: sample tm -> bf16 tmh[B][T][P], S_tm atomics
__launch_bounds__(256) __global__
void tm_kernel(const float* __restrict__ mask_labels,
               const float* __restrict__ coords,
               unsigned short* __restrict__ tmh,
               float* __restrict__ S_tm) {
  const int b = blockIdx.z;
  const int p = blockIdx.x * CHUNK + threadIdx.x;
  const float2* c2 = (const float2*)coords;
  float2 cc = c2[(size_t)b * P_ + p];
  Samp s = make_samp(cc.x, cc.y);
#pragma unroll
  for (int tt = 0; tt < TTILE; ++tt) {
    int t = blockIdx.y * TTILE + tt;
    const float* img = mask_labels + ((size_t)b * T_ + t) * HW_;
    float v = s.w00 * img[s.i00] + s.w01 * img[s.i01] +
              s.w10 * img[s.i10] + s.w11 * img[s.i11];
    tmh[((size_t)b * T_ + t) * P_ + p] = f2bf(v);
    float wv = waveSum(v);
    if ((threadIdx.x & 63) == 0) atomicAdd(&S_tm[b * T_ + t], wv);
  }
}

// convert a pm bf16 A-frag to a sigmoid(pm) bf16 A-frag, elementwise
__device__ __forceinline__ short8 sig_frag(short8 a) {
  short8 out;
#pragma unroll
  for (int j = 0; j < 8; ++j) {
    float x = bf2f((unsigned short)a[j]);
    float e = __expf(-fabsf(x));
    float r = __builtin_amdgcn_rcpf(1.f + e);
    float sg = (x >= 0.f) ? r : e * r;
    out[j] = (short)f2bf(sg);
  }
  return out;
}

// ---------------- phase 3: K-split MFMA GEMM. 5 waves; wave w owns rows 32w..32w+31,
// both n-tiles, both matrices (lin = pm, sig computed in-register from pm frags).
__launch_bounds__(320) __global__
void gemm_kernel(const unsigned short* __restrict__ pmh,
                 const unsigned short* __restrict__ tmh,
                 float* __restrict__ accD) {
  const int b = blockIdx.y;
  const int seg = blockIdx.x;
  const int w = threadIdx.x >> 6;
  const int l = threadIdx.x & 63;
  const int quad = l >> 4;
  const int mrow = l & 15;

  const unsigned short* pmb = pmh + ((size_t)b * QP_ + w * 32) * P_;
  const unsigned short* tmb = tmh + (size_t)b * T_ * P_;

  floatx4 aL[2][2];  // [m-tile local][n-tile]
  floatx4 aS[2][2];
#pragma unroll
  for (int i = 0; i < 2; ++i)
#pragma unroll
    for (int j = 0; j < 2; ++j) {
      aL[i][j] = (floatx4){0.f, 0.f, 0.f, 0.f};
      aS[i][j] = (floatx4){0.f, 0.f, 0.f, 0.f};
    }

  const int kbase = seg * KSEG;
#pragma unroll
  for (int ki = 0; ki < KITER; ++ki) {
    const int k0 = kbase + ki * 32 + quad * 8;
    short8 a0 = *(const short8*)(pmb + (size_t)(0 * 16 + mrow) * P_ + k0);
    short8 a1 = *(const short8*)(pmb + (size_t)(1 * 16 + mrow) * P_ + k0);
    short8 b0 = *(const short8*)(tmb + (size_t)(0 * 16 + mrow) * P_ + k0);
    short8 b1 = *(const short8*)(tmb + (size_t)(1 * 16 + mrow) * P_ + k0);
    short8 s0 = sig_frag(a0);
    short8 s1 = sig_frag(a1);
    aL[0][0] = __builtin_amdgcn_mfma_f32_16x16x32_bf16(a0, b0, aL[0][0], 0, 0, 0);
    aL[0][1] = __builtin_amdgcn_mfma_f32_16x16x32_bf16(a0, b1, aL[0][1], 0, 0, 0);
    aL[1][0] = __builtin_amdgcn_mfma_f32_16x16x32_bf16(a1, b0, aL[1][0], 0, 0, 0);
    aL[1][1] = __builtin_amdgcn_mfma_f32_16x16x32_bf16(a1, b1, aL[1][1], 0, 0, 0);
    aS[0][0] = __builtin_amdgcn_mfma_f32_16x16x32_bf16(s0, b0, aS[0][0], 0, 0, 0);
    aS[0][1] = __builtin_amdgcn_mfma_f32_16x16x32_bf16(s0, b1, aS[0][1], 0, 0, 0);
    aS[1][0] = __builtin_amdgcn_mfma_f32_16x16x32_bf16(s1, b0, aS[1][0], 0, 0, 0);
    aS[1][1] = __builtin_amdgcn_mfma_f32_16x16x32_bf16(s1, b1, aS[1][1], 0, 0, 0);
  }

  // epilogue: atomic accumulate partials. D layout: row(m)=quad*4+reg, col(n)=lane&15
#pragma unroll
  for (int mtl = 0; mtl < 2; ++mtl)
#pragma unroll
    for (int nt = 0; nt < 2; ++nt)
#pragma unroll
      for (int r = 0; r < 4; ++r) {
        int q = w * 32 + mtl * 16 + quad * 4 + r;
        int t = nt * 16 + mrow;
        atomicAdd(&accD[((size_t)(0 * B_ + b) * QP_ + q) * T_ + t], aL[mtl][nt][r]);
        atomicAdd(&accD[((size_t)(1 * B_ + b) * QP_ + q) * T_ + t], aS[mtl][nt][r]);
      }
}

// ---------------- phase 4: finalize. one wave per (b,q)
__launch_bounds__(64) __global__
void final_kernel(const float* __restrict__ class_q,
                  const int* __restrict__ labels,
                  const float* __restrict__ accD,
                  const float* __restrict__ S_sp,
                  const float* __restrict__ S_sig,
                  const float* __restrict__ S_tm,
                  float* __restrict__ out) {
  const int bq = blockIdx.x;
  const int b = bq / Q_;
  const int q = bq % Q_;
  const int l = threadIdx.x;
  const float* cl = class_q + (size_t)bq * C_;

  float v = -INFINITY;
  for (int c = l; c < C_; c += 64) v = fmaxf(v, cl[c]);
  float m = waveMax(v);
  float e = 0.f;
  for (int c = l; c < C_; c += 64) e += __expf(cl[c] - m);
  float den = waveSum(e);

  if (l < T_) {
    int t = l;
    int lbl = labels[b * T_ + t];
    float prob = __expf(cl[lbl] - m) / den;
    float Dlin = accD[((size_t)(0 * B_ + b) * QP_ + q) * T_ + t];
    float Dsig = accD[((size_t)(1 * B_ + b) * QP_ + q) * T_ + t];
    float cmask = (S_sp[bq] - Dlin) * (1.f / (float)P_);
    float dice = 1.f - (2.f * Dsig + 1.f) / (S_sig[bq] + S_tm[b * T_ + t] + 1.f);
    out[(size_t)bq * T_ + t] = 5.f * cmask + 5.f * dice - prob;
  }
}

extern "C" void kernel_launch(void* const* d_in, const int* in_sizes, int n_in,
                              void* d_out, int out_size, void* d_ws,
                              size_t ws_size, hipStream_t stream) {
  const float* masks_q = (const float*)d_in[0];      // [B,Q,H,W]
  const float* class_q = (const float*)d_in[1];      // [B,Q,C]
  const float* mask_labels = (const float*)d_in[2];  // [B,T,H,W]
  const int* class_labels = (const int*)d_in[3];     // [B,T]
  const float* coords = (const float*)d_in[4];       // [B,P,2]
  float* out = (float*)d_out;

  // ws layout (floats first, then bf16 arrays)
  float* accD = (float*)d_ws;                        // [2][B][QP_][T_]
  float* S_sp = accD + 2 * B_ * QP_ * T_;            // [B*Q]
  float* S_sig = S_sp + B_ * Q_;                     // [B*Q]
  float* S_tm = S_sig + B_ * Q_;                     // [B*T]
  size_t zeroFloats = 2 * B_ * QP_ * T_ + 2 * B_ * Q_ + B_ * T_;
  unsigned short* pmh = (unsigned short*)(S_tm + B_ * T_);     // [B][QP_][P]
  unsigned short* tmh = pmh + (size_t)B_ * QP_ * P_;           // [B][T][P]

  hipMemsetAsync(d_ws, 0, zeroFloats * sizeof(float), stream);
  pm_kernel<<<dim3(NCHUNK, NQT, B_), 256, 0, stream>>>(masks_q, coords, pmh,
                                                       S_sp, S_sig);
  tm_kernel<<<dim3(NCHUNK, T_ / TTILE, B_), 256, 0, stream>>>(mask_labels,
                                                              coords, tmh, S_tm);
  gemm_kernel<<<dim3(SEG_, B_), 320, 0, stream>>>(pmh, tmh, accD);
  final_kernel<<<B_ * Q_, 64, 0, stream>>>(class_q, class_labels, accD, S_sp,
                                           S_sig, S_tm, out);
}

// Round 3
// 306.153 us; speedup vs baseline: 2.5944x; 2.5944x over previous
//
#include <hip/hip_runtime.h>
#include <hip/hip_bf16.h>
#include <math.h>

#define B_ 8
#define Q_ 150
#define QP_ 160     // padded Q for MFMA (10 m-tiles of 16)
#define C_ 134
#define T_ 32
#define H_ 160
#define W_ 160
#define P_ 12544
#define HW_ (H_ * W_)
#define HW4_ (HW_ / 4)

#define CHUNK 256
#define NCHUNK 49   // P_/CHUNK
// phase 3 (GEMM)
#define SEG_ 56
#define KSEG 224    // P_/SEG_
#define KITER 7     // KSEG/32

typedef __attribute__((ext_vector_type(8))) short short8;
typedef __attribute__((ext_vector_type(4))) float floatx4;

struct Samp {
  int i00, i01, i10, i11;
  float w00, w01, w10, w11;
};

__device__ __forceinline__ Samp make_samp(float cx, float cy) {
  float x = cx * (float)W_ - 0.5f;
  float y = cy * (float)H_ - 0.5f;
  float x0f = floorf(x), y0f = floorf(y);
  float tx = x - x0f, ty = y - y0f;
  int x0 = (int)x0f, y0 = (int)y0f;
  int x1 = x0 + 1, y1 = y0 + 1;
  bool vx0 = (x0 >= 0) && (x0 < W_);
  bool vx1 = (x1 >= 0) && (x1 < W_);
  bool vy0 = (y0 >= 0) && (y0 < H_);
  bool vy1 = (y1 >= 0) && (y1 < H_);
  int cx0 = min(max(x0, 0), W_ - 1), cx1 = min(max(x1, 0), W_ - 1);
  int cy0 = min(max(y0, 0), H_ - 1), cy1 = min(max(y1, 0), H_ - 1);
  Samp s;
  s.i00 = cy0 * W_ + cx0;
  s.i01 = cy0 * W_ + cx1;
  s.i10 = cy1 * W_ + cx0;
  s.i11 = cy1 * W_ + cx1;
  float w00 = (1.f - tx) * (1.f - ty);
  float w01 = tx * (1.f - ty);
  float w10 = (1.f - tx) * ty;
  float w11 = tx * ty;
  s.w00 = (vx0 && vy0) ? w00 : 0.f;
  s.w01 = (vx1 && vy0) ? w01 : 0.f;
  s.w10 = (vx0 && vy1) ? w10 : 0.f;
  s.w11 = (vx1 && vy1) ? w11 : 0.f;
  return s;
}

__device__ __forceinline__ float waveSum(float v) {
#pragma unroll
  for (int m = 32; m >= 1; m >>= 1) v += __shfl_xor(v, m, 64);
  return v;
}
__device__ __forceinline__ float waveMax(float v) {
#pragma unroll
  for (int m = 32; m >= 1; m >>= 1) v = fmaxf(v, __shfl_xor(v, m, 64));
  return v;
}

__device__ __forceinline__ unsigned short f2bf(float x) {
  union { __hip_bfloat16 h; unsigned short u; } cv;
  cv.h = __float2bfloat16(x);
  return cv.u;
}
__device__ __forceinline__ float bf2f(unsigned short u) {
  return __uint_as_float(((unsigned int)u) << 16);
}

// ---------------- phase 1: sample pm -> bf16 pmh[B][QP_][P], S_sp/S_sig direct
// One block per (q, b). Image staged to LDS as bf16 (50 KB), points read from LDS.
__launch_bounds__(256) __global__
void pm_kernel(const float* __restrict__ masks_q,
               const float* __restrict__ coords,
               unsigned short* __restrict__ pmh,
               float* __restrict__ S_sp, float* __restrict__ S_sig) {
  __shared__ unsigned short img[HW_];
  __shared__ float red[8];
  const int q = blockIdx.x;
  const int b = blockIdx.y;
  const int tid = threadIdx.x;

  const float4* src = (const float4*)(masks_q + ((size_t)b * Q_ + q) * HW_);
#pragma unroll 5
  for (int i = tid; i < HW4_; i += 256) {
    float4 v = src[i];
    ushort4 u;
    u.x = f2bf(v.x); u.y = f2bf(v.y); u.z = f2bf(v.z); u.w = f2bf(v.w);
    *(ushort4*)&img[4 * i] = u;
  }
  __syncthreads();

  const float2* c2 = (const float2*)coords + (size_t)b * P_;
  unsigned short* dst = pmh + ((size_t)b * QP_ + q) * P_;
  float ssp = 0.f, ssg = 0.f;
  for (int c = 0; c < NCHUNK; ++c) {
    int p = c * CHUNK + tid;
    float2 cc = c2[p];
    Samp s = make_samp(cc.x, cc.y);
    float pm = s.w00 * bf2f(img[s.i00]) + s.w01 * bf2f(img[s.i01]) +
               s.w10 * bf2f(img[s.i10]) + s.w11 * bf2f(img[s.i11]);
    float e = __expf(-fabsf(pm));
    float sp = fmaxf(pm, 0.f) + __logf(1.f + e);
    float r = __builtin_amdgcn_rcpf(1.f + e);
    float sg = (pm >= 0.f) ? r : e * r;
    ssp += sp;
    ssg += sg;
    dst[p] = f2bf(pm);
  }
  ssp = waveSum(ssp);
  ssg = waveSum(ssg);
  if ((tid & 63) == 0) {
    red[tid >> 6] = ssp;
    red[4 + (tid >> 6)] = ssg;
  }
  __syncthreads();
  if (tid == 0) {
    S_sp[b * Q_ + q] = red[0] + red[1] + red[2] + red[3];
    S_sig[b * Q_ + q] = red[4] + red[5] + red[6] + red[7];
  }
}

// ---------------- phase 2: sample tm -> bf16 tmh[B][T][P], S_tm direct
__launch_bounds__(256) __global__
void tm_kernel(const float* __restrict__ mask_labels,
               const float* __restrict__ coords,
               unsigned short* __restrict__ tmh,
               float* __restrict__ S_tm) {
  __shared__ unsigned short img[HW_];
  __shared__ float red[4];
  const int t = blockIdx.x;
  const int b = blockIdx.y;
  const int tid = threadIdx.x;

  const float4* src = (const float4*)(mask_labels + ((size_t)b * T_ + t) * HW_);
#pragma unroll 5
  for (int i = tid; i < HW4_; i += 256) {
    float4 v = src[i];
    ushort4 u;
    u.x = f2bf(v.x); u.y = f2bf(v.y); u.z = f2bf(v.z); u.w = f2bf(v.w);
    *(ushort4*)&img[4 * i] = u;
  }
  __syncthreads();

  const float2* c2 = (const float2*)coords + (size_t)b * P_;
  unsigned short* dst = tmh + ((size_t)b * T_ + t) * P_;
  float stm = 0.f;
  for (int c = 0; c < NCHUNK; ++c) {
    int p = c * CHUNK + tid;
    float2 cc = c2[p];
    Samp s = make_samp(cc.x, cc.y);
    float v = s.w00 * bf2f(img[s.i00]) + s.w01 * bf2f(img[s.i01]) +
              s.w10 * bf2f(img[s.i10]) + s.w11 * bf2f(img[s.i11]);
    stm += v;
    dst[p] = f2bf(v);
  }
  stm = waveSum(stm);
  if ((tid & 63) == 0) red[tid >> 6] = stm;
  __syncthreads();
  if (tid == 0) S_tm[b * T_ + t] = red[0] + red[1] + red[2] + red[3];
}

// convert a pm bf16 A-frag to a sigmoid(pm) bf16 A-frag, elementwise
__device__ __forceinline__ short8 sig_frag(short8 a) {
  short8 out;
#pragma unroll
  for (int j = 0; j < 8; ++j) {
    float x = bf2f((unsigned short)a[j]);
    float e = __expf(-fabsf(x));
    float r = __builtin_amdgcn_rcpf(1.f + e);
    float sg = (x >= 0.f) ? r : e * r;
    out[j] = (short)f2bf(sg);
  }
  return out;
}

// ---------------- phase 3: K-split MFMA GEMM. 5 waves; wave w owns rows 32w..32w+31,
// both n-tiles, both matrices (lin = pm, sig computed in-register from pm frags).
__launch_bounds__(320) __global__
void gemm_kernel(const unsigned short* __restrict__ pmh,
                 const unsigned short* __restrict__ tmh,
                 float* __restrict__ accD) {
  const int b = blockIdx.y;
  const int seg = blockIdx.x;
  const int w = threadIdx.x >> 6;
  const int l = threadIdx.x & 63;
  const int quad = l >> 4;
  const int mrow = l & 15;

  const unsigned short* pmb = pmh + ((size_t)b * QP_ + w * 32) * P_;
  const unsigned short* tmb = tmh + (size_t)b * T_ * P_;

  floatx4 aL[2][2];  // [m-tile local][n-tile]
  floatx4 aS[2][2];
#pragma unroll
  for (int i = 0; i < 2; ++i)
#pragma unroll
    for (int j = 0; j < 2; ++j) {
      aL[i][j] = (floatx4){0.f, 0.f, 0.f, 0.f};
      aS[i][j] = (floatx4){0.f, 0.f, 0.f, 0.f};
    }

  const int kbase = seg * KSEG;
#pragma unroll
  for (int ki = 0; ki < KITER; ++ki) {
    const int k0 = kbase + ki * 32 + quad * 8;
    short8 a0 = *(const short8*)(pmb + (size_t)(0 * 16 + mrow) * P_ + k0);
    short8 a1 = *(const short8*)(pmb + (size_t)(1 * 16 + mrow) * P_ + k0);
    short8 b0 = *(const short8*)(tmb + (size_t)(0 * 16 + mrow) * P_ + k0);
    short8 b1 = *(const short8*)(tmb + (size_t)(1 * 16 + mrow) * P_ + k0);
    short8 s0 = sig_frag(a0);
    short8 s1 = sig_frag(a1);
    aL[0][0] = __builtin_amdgcn_mfma_f32_16x16x32_bf16(a0, b0, aL[0][0], 0, 0, 0);
    aL[0][1] = __builtin_amdgcn_mfma_f32_16x16x32_bf16(a0, b1, aL[0][1], 0, 0, 0);
    aL[1][0] = __builtin_amdgcn_mfma_f32_16x16x32_bf16(a1, b0, aL[1][0], 0, 0, 0);
    aL[1][1] = __builtin_amdgcn_mfma_f32_16x16x32_bf16(a1, b1, aL[1][1], 0, 0, 0);
    aS[0][0] = __builtin_amdgcn_mfma_f32_16x16x32_bf16(s0, b0, aS[0][0], 0, 0, 0);
    aS[0][1] = __builtin_amdgcn_mfma_f32_16x16x32_bf16(s0, b1, aS[0][1], 0, 0, 0);
    aS[1][0] = __builtin_amdgcn_mfma_f32_16x16x32_bf16(s1, b0, aS[1][0], 0, 0, 0);
    aS[1][1] = __builtin_amdgcn_mfma_f32_16x16x32_bf16(s1, b1, aS[1][1], 0, 0, 0);
  }

  // epilogue: atomic accumulate partials. D layout: row(m)=quad*4+reg, col(n)=lane&15
#pragma unroll
  for (int mtl = 0; mtl < 2; ++mtl)
#pragma unroll
    for (int nt = 0; nt < 2; ++nt)
#pragma unroll
      for (int r = 0; r < 4; ++r) {
        int q = w * 32 + mtl * 16 + quad * 4 + r;
        int t = nt * 16 + mrow;
        atomicAdd(&accD[((size_t)(0 * B_ + b) * QP_ + q) * T_ + t], aL[mtl][nt][r]);
        atomicAdd(&accD[((size_t)(1 * B_ + b) * QP_ + q) * T_ + t], aS[mtl][nt][r]);
      }
}

// ---------------- phase 4: finalize. one wave per (b,q)
__launch_bounds__(64) __global__
void final_kernel(const float* __restrict__ class_q,
                  const int* __restrict__ labels,
                  const float* __restrict__ accD,
                  const float* __restrict__ S_sp,
                  const float* __restrict__ S_sig,
                  const float* __restrict__ S_tm,
                  float* __restrict__ out) {
  const int bq = blockIdx.x;
  const int b = bq / Q_;
  const int q = bq % Q_;
  const int l = threadIdx.x;
  const float* cl = class_q + (size_t)bq * C_;

  float v = -INFINITY;
  for (int c = l; c < C_; c += 64) v = fmaxf(v, cl[c]);
  float m = waveMax(v);
  float e = 0.f;
  for (int c = l; c < C_; c += 64) e += __expf(cl[c] - m);
  float den = waveSum(e);

  if (l < T_) {
    int t = l;
    int lbl = labels[b * T_ + t];
    float prob = __expf(cl[lbl] - m) / den;
    float Dlin = accD[((size_t)(0 * B_ + b) * QP_ + q) * T_ + t];
    float Dsig = accD[((size_t)(1 * B_ + b) * QP_ + q) * T_ + t];
    float cmask = (S_sp[bq] - Dlin) * (1.f / (float)P_);
    float dice = 1.f - (2.f * Dsig + 1.f) / (S_sig[bq] + S_tm[b * T_ + t] + 1.f);
    out[(size_t)bq * T_ + t] = 5.f * cmask + 5.f * dice - prob;
  }
}

extern "C" void kernel_launch(void* const* d_in, const int* in_sizes, int n_in,
                              void* d_out, int out_size, void* d_ws,
                              size_t ws_size, hipStream_t stream) {
  const float* masks_q = (const float*)d_in[0];      // [B,Q,H,W]
  const float* class_q = (const float*)d_in[1];      // [B,Q,C]
  const float* mask_labels = (const float*)d_in[2];  // [B,T,H,W]
  const int* class_labels = (const int*)d_in[3];     // [B,T]
  const float* coords = (const float*)d_in[4];       // [B,P,2]
  float* out = (float*)d_out;

  // ws layout (floats first, then bf16 arrays)
  float* accD = (float*)d_ws;                        // [2][B][QP_][T_]
  float* S_sp = accD + 2 * B_ * QP_ * T_;            // [B*Q]
  float* S_sig = S_sp + B_ * Q_;                     // [B*Q]
  float* S_tm = S_sig + B_ * Q_;                     // [B*T]
  unsigned short* pmh = (unsigned short*)(S_tm + B_ * T_);     // [B][QP_][P]
  unsigned short* tmh = pmh + (size_t)B_ * QP_ * P_;           // [B][T][P]

  hipMemsetAsync(accD, 0, (size_t)2 * B_ * QP_ * T_ * sizeof(float), stream);
  pm_kernel<<<dim3(Q_, B_), 256, 0, stream>>>(masks_q, coords, pmh, S_sp, S_sig);
  tm_kernel<<<dim3(T_, B_), 256, 0, stream>>>(mask_labels, coords, tmh, S_tm);
  gemm_kernel<<<dim3(SEG_, B_), 320, 0, stream>>>(pmh, tmh, accD);
  final_kernel<<<B_ * Q_, 64, 0, stream>>>(class_q, class_labels, accD, S_sp,
                                           S_sig, S_tm, out);
}

// Round 4
// 260.036 us; speedup vs baseline: 3.0546x; 1.1773x over previous
//
#include <hip/hip_runtime.h>
#include <hip/hip_bf16.h>
#include <hip/hip_fp16.h>
#include <math.h>

#define B_ 8
#define Q_ 150
#define QP_ 160     // padded Q for MFMA (10 m-tiles of 16)
#define C_ 134
#define T_ 32
#define H_ 160
#define W_ 160
#define P_ 12544
#define HW_ (H_ * W_)
#define HW4_ (HW_ / 4)

#define SBLK 512            // sampler block size
#define SCHUNKS 25          // ceil(P_/SBLK): 24 full + 1 half
// phase 3 (GEMM)
#define SEG_ 56
#define KSEG 224    // P_/SEG_
#define KITER 7     // KSEG/32

typedef __attribute__((ext_vector_type(8))) short short8;
typedef __attribute__((ext_vector_type(4))) float floatx4;

struct Samp {
  int i00, i01, i10, i11;
  float w00, w01, w10, w11;
};

__device__ __forceinline__ Samp make_samp(float cx, float cy) {
  float x = cx * (float)W_ - 0.5f;
  float y = cy * (float)H_ - 0.5f;
  float x0f = floorf(x), y0f = floorf(y);
  float tx = x - x0f, ty = y - y0f;
  int x0 = (int)x0f, y0 = (int)y0f;
  int x1 = x0 + 1, y1 = y0 + 1;
  bool vx0 = (x0 >= 0) && (x0 < W_);
  bool vx1 = (x1 >= 0) && (x1 < W_);
  bool vy0 = (y0 >= 0) && (y0 < H_);
  bool vy1 = (y1 >= 0) && (y1 < H_);
  int cx0 = min(max(x0, 0), W_ - 1), cx1 = min(max(x1, 0), W_ - 1);
  int cy0 = min(max(y0, 0), H_ - 1), cy1 = min(max(y1, 0), H_ - 1);
  Samp s;
  s.i00 = cy0 * W_ + cx0;
  s.i01 = cy0 * W_ + cx1;
  s.i10 = cy1 * W_ + cx0;
  s.i11 = cy1 * W_ + cx1;
  float w00 = (1.f - tx) * (1.f - ty);
  float w01 = tx * (1.f - ty);
  float w10 = (1.f - tx) * ty;
  float w11 = tx * ty;
  s.w00 = (vx0 && vy0) ? w00 : 0.f;
  s.w01 = (vx1 && vy0) ? w01 : 0.f;
  s.w10 = (vx0 && vy1) ? w10 : 0.f;
  s.w11 = (vx1 && vy1) ? w11 : 0.f;
  return s;
}

__device__ __forceinline__ float waveSum(float v) {
#pragma unroll
  for (int m = 32; m >= 1; m >>= 1) v += __shfl_xor(v, m, 64);
  return v;
}
__device__ __forceinline__ float waveMax(float v) {
#pragma unroll
  for (int m = 32; m >= 1; m >>= 1) v = fmaxf(v, __shfl_xor(v, m, 64));
  return v;
}

__device__ __forceinline__ unsigned short f2bf(float x) {
  union { __hip_bfloat16 h; unsigned short u; } cv;
  cv.h = __float2bfloat16(x);
  return cv.u;
}
__device__ __forceinline__ float bf2f(unsigned short u) {
  return __uint_as_float(((unsigned int)u) << 16);
}
__device__ __forceinline__ float h2f(unsigned short u) {
  union { __half h; unsigned short u; } cv;
  cv.u = u;
  return __half2float(cv.h);
}
__device__ __forceinline__ unsigned short f2h(float x) {
  union { __half h; unsigned short u; } cv;
  cv.h = __float2half(x);
  return cv.u;
}

// ---------------- phase 0: precompute packed bilinear coeffs per (b,p)
// sIdx: i00 | dx<<15 | dy<<16 ; sW: 4 x fp16 weights
__launch_bounds__(256) __global__
void samp_kernel(const float* __restrict__ coords,
                 unsigned int* __restrict__ sIdx,
                 uint2* __restrict__ sW) {
  int i = blockIdx.x * 256 + threadIdx.x;  // over B_*P_
  float2 cc = ((const float2*)coords)[i];
  Samp s = make_samp(cc.x, cc.y);
  int dx = s.i01 - s.i00;                  // 0 or 1
  int dy = (s.i10 != s.i00) ? 1 : 0;       // row step flag
  sIdx[i] = (unsigned)s.i00 | ((unsigned)dx << 15) | ((unsigned)dy << 16);
  uint2 w;
  w.x = (unsigned)f2h(s.w00) | ((unsigned)f2h(s.w01) << 16);
  w.y = (unsigned)f2h(s.w10) | ((unsigned)f2h(s.w11) << 16);
  sW[i] = w;
}

// ---------------- phase 1+2 fused: sample pm (x<Q_) or tm (x>=Q_)
// One block per (x, b); image staged to LDS as bf16; 512 threads.
__launch_bounds__(SBLK) __global__
void sample_kernel(const float* __restrict__ masks_q,
                   const float* __restrict__ mask_labels,
                   const unsigned int* __restrict__ sIdx,
                   const uint2* __restrict__ sW,
                   unsigned short* __restrict__ pmh,
                   unsigned short* __restrict__ tmh,
                   float* __restrict__ S_sp, float* __restrict__ S_sig,
                   float* __restrict__ S_tm) {
  __shared__ unsigned short img[HW_];
  __shared__ float red[16];
  const int x = blockIdx.x;
  const int b = blockIdx.y;
  const int tid = threadIdx.x;
  const bool isPm = (x < Q_);

  const float* src = isPm ? (masks_q + ((size_t)b * Q_ + x) * HW_)
                          : (mask_labels + ((size_t)b * T_ + (x - Q_)) * HW_);
  const float4* s4 = (const float4*)src;
  for (int i = tid; i < HW4_; i += SBLK) {
    float4 v = s4[i];
    ushort4 u;
    u.x = f2bf(v.x); u.y = f2bf(v.y); u.z = f2bf(v.z); u.w = f2bf(v.w);
    *(ushort4*)&img[4 * i] = u;
  }
  __syncthreads();

  const unsigned int* sIdxB = sIdx + (size_t)b * P_;
  const uint2* sWB = sW + (size_t)b * P_;

  if (isPm) {
    unsigned short* dst = pmh + ((size_t)b * QP_ + x) * P_;
    float ssp = 0.f, ssg = 0.f;
    for (int c = 0; c < SCHUNKS; ++c) {
      int p = c * SBLK + tid;
      if (p < P_) {
        unsigned iv = sIdxB[p];
        uint2 wv = sWB[p];
        int i00 = iv & 0x7fff;
        int i01 = i00 + ((iv >> 15) & 1);
        int ir = (iv & 0x10000) ? W_ : 0;
        float pm = h2f(wv.x & 0xffff) * bf2f(img[i00]) +
                   h2f(wv.x >> 16) * bf2f(img[i01]) +
                   h2f(wv.y & 0xffff) * bf2f(img[i00 + ir]) +
                   h2f(wv.y >> 16) * bf2f(img[i01 + ir]);
        float e = __expf(-fabsf(pm));
        float sp = fmaxf(pm, 0.f) + __logf(1.f + e);
        float r = __builtin_amdgcn_rcpf(1.f + e);
        float sg = (pm >= 0.f) ? r : e * r;
        ssp += sp;
        ssg += sg;
        dst[p] = f2bf(pm);
      }
    }
    ssp = waveSum(ssp);
    ssg = waveSum(ssg);
    int w = tid >> 6;
    if ((tid & 63) == 0) {
      red[w] = ssp;
      red[8 + w] = ssg;
    }
    __syncthreads();
    if (tid == 0) {
      float a = 0.f, bb = 0.f;
#pragma unroll
      for (int i = 0; i < 8; ++i) { a += red[i]; bb += red[8 + i]; }
      S_sp[b * Q_ + x] = a;
      S_sig[b * Q_ + x] = bb;
    }
  } else {
    const int t = x - Q_;
    unsigned short* dst = tmh + ((size_t)b * T_ + t) * P_;
    float stm = 0.f;
    for (int c = 0; c < SCHUNKS; ++c) {
      int p = c * SBLK + tid;
      if (p < P_) {
        unsigned iv = sIdxB[p];
        uint2 wv = sWB[p];
        int i00 = iv & 0x7fff;
        int i01 = i00 + ((iv >> 15) & 1);
        int ir = (iv & 0x10000) ? W_ : 0;
        float v = h2f(wv.x & 0xffff) * bf2f(img[i00]) +
                  h2f(wv.x >> 16) * bf2f(img[i01]) +
                  h2f(wv.y & 0xffff) * bf2f(img[i00 + ir]) +
                  h2f(wv.y >> 16) * bf2f(img[i01 + ir]);
        stm += v;
        dst[p] = f2bf(v);
      }
    }
    stm = waveSum(stm);
    int w = tid >> 6;
    if ((tid & 63) == 0) red[w] = stm;
    __syncthreads();
    if (tid == 0) {
      float a = 0.f;
#pragma unroll
      for (int i = 0; i < 8; ++i) a += red[i];
      S_tm[b * T_ + t] = a;
    }
  }
}

// convert a pm bf16 A-frag to a sigmoid(pm) bf16 A-frag, elementwise
__device__ __forceinline__ short8 sig_frag(short8 a) {
  short8 out;
#pragma unroll
  for (int j = 0; j < 8; ++j) {
    float x = bf2f((unsigned short)a[j]);
    float e = __expf(-fabsf(x));
    float r = __builtin_amdgcn_rcpf(1.f + e);
    float sg = (x >= 0.f) ? r : e * r;
    out[j] = (short)f2bf(sg);
  }
  return out;
}

// ---------------- phase 3: K-split MFMA GEMM. 5 waves; wave w owns rows 32w..32w+31,
// both n-tiles, both matrices (lin = pm, sig computed in-register from pm frags).
__launch_bounds__(320) __global__
void gemm_kernel(const unsigned short* __restrict__ pmh,
                 const unsigned short* __restrict__ tmh,
                 float* __restrict__ accD) {
  const int b = blockIdx.y;
  const int seg = blockIdx.x;
  const int w = threadIdx.x >> 6;
  const int l = threadIdx.x & 63;
  const int quad = l >> 4;
  const int mrow = l & 15;

  const unsigned short* pmb = pmh + ((size_t)b * QP_ + w * 32) * P_;
  const unsigned short* tmb = tmh + (size_t)b * T_ * P_;

  floatx4 aL[2][2];  // [m-tile local][n-tile]
  floatx4 aS[2][2];
#pragma unroll
  for (int i = 0; i < 2; ++i)
#pragma unroll
    for (int j = 0; j < 2; ++j) {
      aL[i][j] = (floatx4){0.f, 0.f, 0.f, 0.f};
      aS[i][j] = (floatx4){0.f, 0.f, 0.f, 0.f};
    }

  const int kbase = seg * KSEG;
#pragma unroll
  for (int ki = 0; ki < KITER; ++ki) {
    const int k0 = kbase + ki * 32 + quad * 8;
    short8 a0 = *(const short8*)(pmb + (size_t)(0 * 16 + mrow) * P_ + k0);
    short8 a1 = *(const short8*)(pmb + (size_t)(1 * 16 + mrow) * P_ + k0);
    short8 b0 = *(const short8*)(tmb + (size_t)(0 * 16 + mrow) * P_ + k0);
    short8 b1 = *(const short8*)(tmb + (size_t)(1 * 16 + mrow) * P_ + k0);
    short8 s0 = sig_frag(a0);
    short8 s1 = sig_frag(a1);
    aL[0][0] = __builtin_amdgcn_mfma_f32_16x16x32_bf16(a0, b0, aL[0][0], 0, 0, 0);
    aL[0][1] = __builtin_amdgcn_mfma_f32_16x16x32_bf16(a0, b1, aL[0][1], 0, 0, 0);
    aL[1][0] = __builtin_amdgcn_mfma_f32_16x16x32_bf16(a1, b0, aL[1][0], 0, 0, 0);
    aL[1][1] = __builtin_amdgcn_mfma_f32_16x16x32_bf16(a1, b1, aL[1][1], 0, 0, 0);
    aS[0][0] = __builtin_amdgcn_mfma_f32_16x16x32_bf16(s0, b0, aS[0][0], 0, 0, 0);
    aS[0][1] = __builtin_amdgcn_mfma_f32_16x16x32_bf16(s0, b1, aS[0][1], 0, 0, 0);
    aS[1][0] = __builtin_amdgcn_mfma_f32_16x16x32_bf16(s1, b0, aS[1][0], 0, 0, 0);
    aS[1][1] = __builtin_amdgcn_mfma_f32_16x16x32_bf16(s1, b1, aS[1][1], 0, 0, 0);
  }

  // epilogue: atomic accumulate partials. D layout: row(m)=quad*4+reg, col(n)=lane&15
#pragma unroll
  for (int mtl = 0; mtl < 2; ++mtl)
#pragma unroll
    for (int nt = 0; nt < 2; ++nt)
#pragma unroll
      for (int r = 0; r < 4; ++r) {
        int q = w * 32 + mtl * 16 + quad * 4 + r;
        int t = nt * 16 + mrow;
        atomicAdd(&accD[((size_t)(0 * B_ + b) * QP_ + q) * T_ + t], aL[mtl][nt][r]);
        atomicAdd(&accD[((size_t)(1 * B_ + b) * QP_ + q) * T_ + t], aS[mtl][nt][r]);
      }
}

// ---------------- phase 4: finalize. one wave per (b,q)
__launch_bounds__(64) __global__
void final_kernel(const float* __restrict__ class_q,
                  const int* __restrict__ labels,
                  const float* __restrict__ accD,
                  const float* __restrict__ S_sp,
                  const float* __restrict__ S_sig,
                  const float* __restrict__ S_tm,
                  float* __restrict__ out) {
  const int bq = blockIdx.x;
  const int b = bq / Q_;
  const int q = bq % Q_;
  const int l = threadIdx.x;
  const float* cl = class_q + (size_t)bq * C_;

  float v = -INFINITY;
  for (int c = l; c < C_; c += 64) v = fmaxf(v, cl[c]);
  float m = waveMax(v);
  float e = 0.f;
  for (int c = l; c < C_; c += 64) e += __expf(cl[c] - m);
  float den = waveSum(e);

  if (l < T_) {
    int t = l;
    int lbl = labels[b * T_ + t];
    float prob = __expf(cl[lbl] - m) / den;
    float Dlin = accD[((size_t)(0 * B_ + b) * QP_ + q) * T_ + t];
    float Dsig = accD[((size_t)(1 * B_ + b) * QP_ + q) * T_ + t];
    float cmask = (S_sp[bq] - Dlin) * (1.f / (float)P_);
    float dice = 1.f - (2.f * Dsig + 1.f) / (S_sig[bq] + S_tm[b * T_ + t] + 1.f);
    out[(size_t)bq * T_ + t] = 5.f * cmask + 5.f * dice - prob;
  }
}

extern "C" void kernel_launch(void* const* d_in, const int* in_sizes, int n_in,
                              void* d_out, int out_size, void* d_ws,
                              size_t ws_size, hipStream_t stream) {
  const float* masks_q = (const float*)d_in[0];      // [B,Q,H,W]
  const float* class_q = (const float*)d_in[1];      // [B,Q,C]
  const float* mask_labels = (const float*)d_in[2];  // [B,T,H,W]
  const int* class_labels = (const int*)d_in[3];     // [B,T]
  const float* coords = (const float*)d_in[4];       // [B,P,2]
  float* out = (float*)d_out;

  // ws layout: fp32 scalars, then 8B-aligned packed arrays, then bf16 arrays
  float* accD = (float*)d_ws;                        // [2][B][QP_][T_] 81920
  float* S_sp = accD + 2 * B_ * QP_ * T_;            // [B*Q]
  float* S_sig = S_sp + B_ * Q_;                     // [B*Q]
  float* S_tm = S_sig + B_ * Q_;                     // [B*T]
  uint2* sW = (uint2*)(S_tm + B_ * T_);              // [B*P]  (8B aligned)
  unsigned int* sIdx = (unsigned int*)(sW + (size_t)B_ * P_);  // [B*P]
  unsigned short* pmh = (unsigned short*)(sIdx + (size_t)B_ * P_);  // [B][QP_][P]
  unsigned short* tmh = pmh + (size_t)B_ * QP_ * P_;               // [B][T][P]

  hipMemsetAsync(accD, 0, (size_t)2 * B_ * QP_ * T_ * sizeof(float), stream);
  samp_kernel<<<(B_ * P_) / 256, 256, 0, stream>>>(coords, sIdx, sW);
  sample_kernel<<<dim3(Q_ + T_, B_), SBLK, 0, stream>>>(
      masks_q, mask_labels, sIdx, sW, pmh, tmh, S_sp, S_sig, S_tm);
  gemm_kernel<<<dim3(SEG_, B_), 320, 0, stream>>>(pmh, tmh, accD);
  final_kernel<<<B_ * Q_, 64, 0, stream>>>(class_q, class_labels, accD, S_sp,
                                           S_sig, S_tm, out);
}

// Round 5
// 244.691 us; speedup vs baseline: 3.2461x; 1.0627x over previous
//
#include <hip/hip_runtime.h>
#include <hip/hip_bf16.h>
#include <hip/hip_fp16.h>
#include <math.h>

#define B_ 8
#define Q_ 150
#define QP_ 160     // padded Q for MFMA (10 m-tiles of 16)
#define C_ 134
#define T_ 32
#define H_ 160
#define W_ 160
#define P_ 12544
#define HW_ (H_ * W_)
#define HW4_ (HW_ / 4)

#define SBLK 1024           // sampler block size (2 blocks/CU, 32 waves/CU)
#define SFULL 12            // 12*1024 = 12288 guard-free points
#define STAIL 256           // 12544 - 12288
// GEMM
#define SEG_ 28
#define KSEG 448            // P_/SEG_
#define KITER 14            // KSEG/32
#define DSTRIDE (2 * B_ * QP_ * T_)   // 81920 floats per segment slab

typedef __attribute__((ext_vector_type(8))) short short8;
typedef __attribute__((ext_vector_type(4))) float floatx4;

struct Samp {
  int i00, i01, i10, i11;
  float w00, w01, w10, w11;
};

__device__ __forceinline__ Samp make_samp(float cx, float cy) {
  float x = cx * (float)W_ - 0.5f;
  float y = cy * (float)H_ - 0.5f;
  float x0f = floorf(x), y0f = floorf(y);
  float tx = x - x0f, ty = y - y0f;
  int x0 = (int)x0f, y0 = (int)y0f;
  int x1 = x0 + 1, y1 = y0 + 1;
  bool vx0 = (x0 >= 0) && (x0 < W_);
  bool vx1 = (x1 >= 0) && (x1 < W_);
  bool vy0 = (y0 >= 0) && (y0 < H_);
  bool vy1 = (y1 >= 0) && (y1 < H_);
  int cx0 = min(max(x0, 0), W_ - 1), cx1 = min(max(x1, 0), W_ - 1);
  int cy0 = min(max(y0, 0), H_ - 1), cy1 = min(max(y1, 0), H_ - 1);
  Samp s;
  s.i00 = cy0 * W_ + cx0;
  s.i01 = cy0 * W_ + cx1;
  s.i10 = cy1 * W_ + cx0;
  s.i11 = cy1 * W_ + cx1;
  float w00 = (1.f - tx) * (1.f - ty);
  float w01 = tx * (1.f - ty);
  float w10 = (1.f - tx) * ty;
  float w11 = tx * ty;
  s.w00 = (vx0 && vy0) ? w00 : 0.f;
  s.w01 = (vx1 && vy0) ? w01 : 0.f;
  s.w10 = (vx0 && vy1) ? w10 : 0.f;
  s.w11 = (vx1 && vy1) ? w11 : 0.f;
  return s;
}

__device__ __forceinline__ float waveSum(float v) {
#pragma unroll
  for (int m = 32; m >= 1; m >>= 1) v += __shfl_xor(v, m, 64);
  return v;
}
__device__ __forceinline__ float waveMax(float v) {
#pragma unroll
  for (int m = 32; m >= 1; m >>= 1) v = fmaxf(v, __shfl_xor(v, m, 64));
  return v;
}

__device__ __forceinline__ unsigned short f2bf(float x) {
  union { __hip_bfloat16 h; unsigned short u; } cv;
  cv.h = __float2bfloat16(x);
  return cv.u;
}
__device__ __forceinline__ float bf2f(unsigned short u) {
  return __uint_as_float(((unsigned int)u) << 16);
}
__device__ __forceinline__ float h2f(unsigned short u) {
  union { __half h; unsigned short u; } cv;
  cv.u = u;
  return __half2float(cv.h);
}
__device__ __forceinline__ unsigned short f2h(float x) {
  union { __half h; unsigned short u; } cv;
  cv.h = __float2half(x);
  return cv.u;
}

// ---------------- phase 0: precompute packed bilinear coeffs per (b,p)
__launch_bounds__(256) __global__
void samp_kernel(const float* __restrict__ coords,
                 unsigned int* __restrict__ sIdx,
                 uint2* __restrict__ sW) {
  int i = blockIdx.x * 256 + threadIdx.x;  // over B_*P_
  float2 cc = ((const float2*)coords)[i];
  Samp s = make_samp(cc.x, cc.y);
  int dx = s.i01 - s.i00;                  // 0 or 1
  int dy = (s.i10 != s.i00) ? 1 : 0;       // row step flag
  sIdx[i] = (unsigned)s.i00 | ((unsigned)dx << 15) | ((unsigned)dy << 16);
  uint2 w;
  w.x = (unsigned)f2h(s.w00) | ((unsigned)f2h(s.w01) << 16);
  w.y = (unsigned)f2h(s.w10) | ((unsigned)f2h(s.w11) << 16);
  sW[i] = w;
}

__device__ __forceinline__ float lds_sample(const unsigned short* img,
                                            unsigned iv, uint2 wv) {
  int i00 = iv & 0x7fff;
  int i01 = i00 + ((iv >> 15) & 1);
  int ir = (iv & 0x10000) ? W_ : 0;
  return h2f(wv.x & 0xffff) * bf2f(img[i00]) +
         h2f(wv.x >> 16) * bf2f(img[i01]) +
         h2f(wv.y & 0xffff) * bf2f(img[i00 + ir]) +
         h2f(wv.y >> 16) * bf2f(img[i01 + ir]);
}

// ---------------- phase 1+2 fused: sample pm (x<Q_) or tm (x>=Q_)
__launch_bounds__(SBLK) __global__
void sample_kernel(const float* __restrict__ masks_q,
                   const float* __restrict__ mask_labels,
                   const unsigned int* __restrict__ sIdx,
                   const uint2* __restrict__ sW,
                   unsigned short* __restrict__ pmh,
                   unsigned short* __restrict__ tmh,
                   float* __restrict__ S_sp, float* __restrict__ S_sig,
                   float* __restrict__ S_tm) {
  __shared__ unsigned short img[HW_];
  __shared__ float red[32];
  const int x = blockIdx.x;
  const int b = blockIdx.y;
  const int tid = threadIdx.x;
  const bool isPm = (x < Q_);

  const float* src = isPm ? (masks_q + ((size_t)b * Q_ + x) * HW_)
                          : (mask_labels + ((size_t)b * T_ + (x - Q_)) * HW_);
  const float4* s4 = (const float4*)src;
  for (int i = tid; i < HW4_; i += SBLK) {
    float4 v = s4[i];
    ushort4 u;
    u.x = f2bf(v.x); u.y = f2bf(v.y); u.z = f2bf(v.z); u.w = f2bf(v.w);
    *(ushort4*)&img[4 * i] = u;
  }
  __syncthreads();

  const unsigned int* sIdxB = sIdx + (size_t)b * P_;
  const uint2* sWB = sW + (size_t)b * P_;

  if (isPm) {
    unsigned short* dst = pmh + ((size_t)b * QP_ + x) * P_;
    float ssp = 0.f, ssg = 0.f;
#pragma unroll 2
    for (int c = 0; c < SFULL; ++c) {
      int p = c * SBLK + tid;
      float pm = lds_sample(img, sIdxB[p], sWB[p]);
      float e = __expf(-fabsf(pm));
      float sp = fmaxf(pm, 0.f) + __logf(1.f + e);
      float r = __builtin_amdgcn_rcpf(1.f + e);
      float sg = (pm >= 0.f) ? r : e * r;
      ssp += sp;
      ssg += sg;
      dst[p] = f2bf(pm);
    }
    if (tid < STAIL) {
      int p = SFULL * SBLK + tid;
      float pm = lds_sample(img, sIdxB[p], sWB[p]);
      float e = __expf(-fabsf(pm));
      float sp = fmaxf(pm, 0.f) + __logf(1.f + e);
      float r = __builtin_amdgcn_rcpf(1.f + e);
      float sg = (pm >= 0.f) ? r : e * r;
      ssp += sp;
      ssg += sg;
      dst[p] = f2bf(pm);
    }
    ssp = waveSum(ssp);
    ssg = waveSum(ssg);
    int w = tid >> 6;
    if ((tid & 63) == 0) {
      red[w] = ssp;
      red[16 + w] = ssg;
    }
    __syncthreads();
    if (tid == 0) {
      float a = 0.f, bb = 0.f;
#pragma unroll
      for (int i = 0; i < 16; ++i) { a += red[i]; bb += red[16 + i]; }
      S_sp[b * Q_ + x] = a;
      S_sig[b * Q_ + x] = bb;
    }
  } else {
    const int t = x - Q_;
    unsigned short* dst = tmh + ((size_t)b * T_ + t) * P_;
    float stm = 0.f;
#pragma unroll 2
    for (int c = 0; c < SFULL; ++c) {
      int p = c * SBLK + tid;
      float v = lds_sample(img, sIdxB[p], sWB[p]);
      stm += v;
      dst[p] = f2bf(v);
    }
    if (tid < STAIL) {
      int p = SFULL * SBLK + tid;
      float v = lds_sample(img, sIdxB[p], sWB[p]);
      stm += v;
      dst[p] = f2bf(v);
    }
    stm = waveSum(stm);
    int w = tid >> 6;
    if ((tid & 63) == 0) red[w] = stm;
    __syncthreads();
    if (tid == 0) {
      float a = 0.f;
#pragma unroll
      for (int i = 0; i < 16; ++i) a += red[i];
      S_tm[b * T_ + t] = a;
    }
  }
}

// convert a pm bf16 A-frag to a sigmoid(pm) bf16 A-frag, elementwise
__device__ __forceinline__ short8 sig_frag(short8 a) {
  short8 out;
#pragma unroll
  for (int j = 0; j < 8; ++j) {
    float x = bf2f((unsigned short)a[j]);
    float e = __expf(-fabsf(x));
    float r = __builtin_amdgcn_rcpf(1.f + e);
    float sg = (x >= 0.f) ? r : e * r;
    out[j] = (short)f2bf(sg);
  }
  return out;
}

// ---------------- phase 3: K-split MFMA GEMM, atomic-free partials.
// Block (seg,b): 5 waves; wave w owns rows 32w..32w+31, both n-tiles,
// both matrices (sig computed in-register from pm frags).
// Partials: accP[seg][m(2)][b][QP_][T_]
__launch_bounds__(320) __global__
void gemm_kernel(const unsigned short* __restrict__ pmh,
                 const unsigned short* __restrict__ tmh,
                 float* __restrict__ accP) {
  const int b = blockIdx.y;
  const int seg = blockIdx.x;
  const int w = threadIdx.x >> 6;
  const int l = threadIdx.x & 63;
  const int quad = l >> 4;
  const int mrow = l & 15;

  const unsigned short* pmb = pmh + ((size_t)b * QP_ + w * 32) * P_;
  const unsigned short* tmb = tmh + (size_t)b * T_ * P_;

  floatx4 aL[2][2];  // [m-tile local][n-tile]
  floatx4 aS[2][2];
#pragma unroll
  for (int i = 0; i < 2; ++i)
#pragma unroll
    for (int j = 0; j < 2; ++j) {
      aL[i][j] = (floatx4){0.f, 0.f, 0.f, 0.f};
      aS[i][j] = (floatx4){0.f, 0.f, 0.f, 0.f};
    }

  const int kbase = seg * KSEG;
#pragma unroll 2
  for (int ki = 0; ki < KITER; ++ki) {
    const int k0 = kbase + ki * 32 + quad * 8;
    short8 a0 = *(const short8*)(pmb + (size_t)(0 * 16 + mrow) * P_ + k0);
    short8 a1 = *(const short8*)(pmb + (size_t)(1 * 16 + mrow) * P_ + k0);
    short8 b0 = *(const short8*)(tmb + (size_t)(0 * 16 + mrow) * P_ + k0);
    short8 b1 = *(const short8*)(tmb + (size_t)(1 * 16 + mrow) * P_ + k0);
    short8 s0 = sig_frag(a0);
    short8 s1 = sig_frag(a1);
    aL[0][0] = __builtin_amdgcn_mfma_f32_16x16x32_bf16(a0, b0, aL[0][0], 0, 0, 0);
    aL[0][1] = __builtin_amdgcn_mfma_f32_16x16x32_bf16(a0, b1, aL[0][1], 0, 0, 0);
    aL[1][0] = __builtin_amdgcn_mfma_f32_16x16x32_bf16(a1, b0, aL[1][0], 0, 0, 0);
    aL[1][1] = __builtin_amdgcn_mfma_f32_16x16x32_bf16(a1, b1, aL[1][1], 0, 0, 0);
    aS[0][0] = __builtin_amdgcn_mfma_f32_16x16x32_bf16(s0, b0, aS[0][0], 0, 0, 0);
    aS[0][1] = __builtin_amdgcn_mfma_f32_16x16x32_bf16(s0, b1, aS[0][1], 0, 0, 0);
    aS[1][0] = __builtin_amdgcn_mfma_f32_16x16x32_bf16(s1, b0, aS[1][0], 0, 0, 0);
    aS[1][1] = __builtin_amdgcn_mfma_f32_16x16x32_bf16(s1, b1, aS[1][1], 0, 0, 0);
  }

  // epilogue: plain stores. D layout: row(m)=quad*4+reg, col(n)=lane&15
  float* base = accP + (size_t)seg * DSTRIDE;
#pragma unroll
  for (int mtl = 0; mtl < 2; ++mtl)
#pragma unroll
    for (int nt = 0; nt < 2; ++nt)
#pragma unroll
      for (int r = 0; r < 4; ++r) {
        int q = w * 32 + mtl * 16 + quad * 4 + r;
        int t = nt * 16 + mrow;
        base[((size_t)(0 * B_ + b) * QP_ + q) * T_ + t] = aL[mtl][nt][r];
        base[((size_t)(1 * B_ + b) * QP_ + q) * T_ + t] = aS[mtl][nt][r];
      }
}

// ---------------- phase 3b: reduce partials over segments
__launch_bounds__(256) __global__
void reduce_kernel(const float* __restrict__ accP, float* __restrict__ accD) {
  int i = blockIdx.x * 256 + threadIdx.x;  // < DSTRIDE
  float s = 0.f;
#pragma unroll
  for (int seg = 0; seg < SEG_; ++seg) s += accP[(size_t)seg * DSTRIDE + i];
  accD[i] = s;
}

// ---------------- phase 4: finalize. one wave per (b,q)
__launch_bounds__(64) __global__
void final_kernel(const float* __restrict__ class_q,
                  const int* __restrict__ labels,
                  const float* __restrict__ accD,
                  const float* __restrict__ S_sp,
                  const float* __restrict__ S_sig,
                  const float* __restrict__ S_tm,
                  float* __restrict__ out) {
  const int bq = blockIdx.x;
  const int b = bq / Q_;
  const int q = bq % Q_;
  const int l = threadIdx.x;
  const float* cl = class_q + (size_t)bq * C_;

  float v = -INFINITY;
  for (int c = l; c < C_; c += 64) v = fmaxf(v, cl[c]);
  float m = waveMax(v);
  float e = 0.f;
  for (int c = l; c < C_; c += 64) e += __expf(cl[c] - m);
  float den = waveSum(e);

  if (l < T_) {
    int t = l;
    int lbl = labels[b * T_ + t];
    float prob = __expf(cl[lbl] - m) / den;
    float Dlin = accD[((size_t)(0 * B_ + b) * QP_ + q) * T_ + t];
    float Dsig = accD[((size_t)(1 * B_ + b) * QP_ + q) * T_ + t];
    float cmask = (S_sp[bq] - Dlin) * (1.f / (float)P_);
    float dice = 1.f - (2.f * Dsig + 1.f) / (S_sig[bq] + S_tm[b * T_ + t] + 1.f);
    out[(size_t)bq * T_ + t] = 5.f * cmask + 5.f * dice - prob;
  }
}

extern "C" void kernel_launch(void* const* d_in, const int* in_sizes, int n_in,
                              void* d_out, int out_size, void* d_ws,
                              size_t ws_size, hipStream_t stream) {
  const float* masks_q = (const float*)d_in[0];      // [B,Q,H,W]
  const float* class_q = (const float*)d_in[1];      // [B,Q,C]
  const float* mask_labels = (const float*)d_in[2];  // [B,T,H,W]
  const int* class_labels = (const int*)d_in[3];     // [B,T]
  const float* coords = (const float*)d_in[4];       // [B,P,2]
  float* out = (float*)d_out;

  // ws layout
  float* accD = (float*)d_ws;                         // [2][B][QP_][T_]
  float* accP = accD + DSTRIDE;                       // [SEG_][2][B][QP_][T_]
  uint2* sW = (uint2*)(accP + (size_t)SEG_ * DSTRIDE);  // [B*P] (8B aligned)
  unsigned int* sIdx = (unsigned int*)(sW + (size_t)B_ * P_);  // [B*P]
  float* S_sp = (float*)(sIdx + (size_t)B_ * P_);     // [B*Q]
  float* S_sig = S_sp + B_ * Q_;                      // [B*Q]
  float* S_tm = S_sig + B_ * Q_;                      // [B*T]
  unsigned short* pmh = (unsigned short*)(S_tm + B_ * T_);  // [B][QP_][P]
  unsigned short* tmh = pmh + (size_t)B_ * QP_ * P_;        // [B][T][P]

  samp_kernel<<<(B_ * P_) / 256, 256, 0, stream>>>(coords, sIdx, sW);
  sample_kernel<<<dim3(Q_ + T_, B_), SBLK, 0, stream>>>(
      masks_q, mask_labels, sIdx, sW, pmh, tmh, S_sp, S_sig, S_tm);
  gemm_kernel<<<dim3(SEG_, B_), 320, 0, stream>>>(pmh, tmh, accP);
  reduce_kernel<<<DSTRIDE / 256, 256, 0, stream>>>(accP, accD);
  final_kernel<<<B_ * Q_, 64, 0, stream>>>(class_q, class_labels, accD, S_sp,
                                           S_sig, S_tm, out);
}

// Round 6
// 240.697 us; speedup vs baseline: 3.3000x; 1.0166x over previous
//
#include <hip/hip_runtime.h>
#include <hip/hip_bf16.h>
#include <hip/hip_fp16.h>
#include <math.h>

#define B_ 8
#define Q_ 150
#define QP_ 160     // padded Q for MFMA (10 m-tiles of 16)
#define C_ 134
#define T_ 32
#define H_ 160
#define W_ 160
#define P_ 12544
#define HW_ (H_ * W_)
#define HW4_ (HW_ / 4)

#define SBLK 1024           // sampler block size
#define SBATCH 3            // 3 iters x 4 points x 1024 threads = 12288
#define STAIL 256           // 12544 - 12288
// GEMM
#define SEG_ 56
#define KSEG 224            // P_/SEG_
#define KITER 7             // KSEG/32
#define DSTRIDE (2 * B_ * QP_ * T_)   // 81920 floats per segment slab

typedef __attribute__((ext_vector_type(8))) short short8;
typedef __attribute__((ext_vector_type(4))) float floatx4;

struct Samp {
  int i00, i01, i10, i11;
  float w00, w01, w10, w11;
};

__device__ __forceinline__ Samp make_samp(float cx, float cy) {
  float x = cx * (float)W_ - 0.5f;
  float y = cy * (float)H_ - 0.5f;
  float x0f = floorf(x), y0f = floorf(y);
  float tx = x - x0f, ty = y - y0f;
  int x0 = (int)x0f, y0 = (int)y0f;
  int x1 = x0 + 1, y1 = y0 + 1;
  bool vx0 = (x0 >= 0) && (x0 < W_);
  bool vx1 = (x1 >= 0) && (x1 < W_);
  bool vy0 = (y0 >= 0) && (y0 < H_);
  bool vy1 = (y1 >= 0) && (y1 < H_);
  int cx0 = min(max(x0, 0), W_ - 1), cx1 = min(max(x1, 0), W_ - 1);
  int cy0 = min(max(y0, 0), H_ - 1), cy1 = min(max(y1, 0), H_ - 1);
  Samp s;
  s.i00 = cy0 * W_ + cx0;
  s.i01 = cy0 * W_ + cx1;
  s.i10 = cy1 * W_ + cx0;
  s.i11 = cy1 * W_ + cx1;
  float w00 = (1.f - tx) * (1.f - ty);
  float w01 = tx * (1.f - ty);
  float w10 = (1.f - tx) * ty;
  float w11 = tx * ty;
  s.w00 = (vx0 && vy0) ? w00 : 0.f;
  s.w01 = (vx1 && vy0) ? w01 : 0.f;
  s.w10 = (vx0 && vy1) ? w10 : 0.f;
  s.w11 = (vx1 && vy1) ? w11 : 0.f;
  return s;
}

__device__ __forceinline__ float waveSum(float v) {
#pragma unroll
  for (int m = 32; m >= 1; m >>= 1) v += __shfl_xor(v, m, 64);
  return v;
}
__device__ __forceinline__ float waveMax(float v) {
#pragma unroll
  for (int m = 32; m >= 1; m >>= 1) v = fmaxf(v, __shfl_xor(v, m, 64));
  return v;
}

__device__ __forceinline__ unsigned short f2bf(float x) {
  union { __hip_bfloat16 h; unsigned short u; } cv;
  cv.h = __float2bfloat16(x);
  return cv.u;
}
__device__ __forceinline__ float bf2f(unsigned short u) {
  return __uint_as_float(((unsigned int)u) << 16);
}
__device__ __forceinline__ float h2f(unsigned short u) {
  union { __half h; unsigned short u; } cv;
  cv.u = u;
  return __half2float(cv.h);
}
__device__ __forceinline__ unsigned short f2h(float x) {
  union { __half h; unsigned short u; } cv;
  cv.h = __float2half(x);
  return cv.u;
}

// ---------------- phase 0: precompute packed bilinear coeffs per (b,p)
__launch_bounds__(256) __global__
void samp_kernel(const float* __restrict__ coords,
                 unsigned int* __restrict__ sIdx,
                 uint2* __restrict__ sW) {
  int i = blockIdx.x * 256 + threadIdx.x;  // over B_*P_
  float2 cc = ((const float2*)coords)[i];
  Samp s = make_samp(cc.x, cc.y);
  int dx = s.i01 - s.i00;                  // 0 or 1
  int dy = (s.i10 != s.i00) ? 1 : 0;       // row step flag
  sIdx[i] = (unsigned)s.i00 | ((unsigned)dx << 15) | ((unsigned)dy << 16);
  uint2 w;
  w.x = (unsigned)f2h(s.w00) | ((unsigned)f2h(s.w01) << 16);
  w.y = (unsigned)f2h(s.w10) | ((unsigned)f2h(s.w11) << 16);
  sW[i] = w;
}

__device__ __forceinline__ float lds_sample(const unsigned short* img,
                                            unsigned iv, uint2 wv) {
  int i00 = iv & 0x7fff;
  int i01 = i00 + ((iv >> 15) & 1);
  int ir = (iv & 0x10000) ? W_ : 0;
  return h2f(wv.x & 0xffff) * bf2f(img[i00]) +
         h2f(wv.x >> 16) * bf2f(img[i01]) +
         h2f(wv.y & 0xffff) * bf2f(img[i00 + ir]) +
         h2f(wv.y >> 16) * bf2f(img[i01 + ir]);
}

// ---------------- phase 1+2 fused: sample pm (x<Q_) or tm (x>=Q_)
// 4 points per thread per iteration for ILP (16 ds_reads in flight).
__launch_bounds__(SBLK, 8) __global__
void sample_kernel(const float* __restrict__ masks_q,
                   const float* __restrict__ mask_labels,
                   const unsigned int* __restrict__ sIdx,
                   const uint2* __restrict__ sW,
                   unsigned short* __restrict__ pmh,
                   unsigned short* __restrict__ tmh,
                   float* __restrict__ S_sp, float* __restrict__ S_sig,
                   float* __restrict__ S_tm) {
  __shared__ unsigned short img[HW_];
  __shared__ float red[32];
  const int x = blockIdx.x;
  const int b = blockIdx.y;
  const int tid = threadIdx.x;
  const bool isPm = (x < Q_);

  const float* src = isPm ? (masks_q + ((size_t)b * Q_ + x) * HW_)
                          : (mask_labels + ((size_t)b * T_ + (x - Q_)) * HW_);
  const float4* s4 = (const float4*)src;
#pragma unroll
  for (int c = 0; c < 6; ++c) {
    int i = c * SBLK + tid;
    float4 v = s4[i];
    ushort4 u;
    u.x = f2bf(v.x); u.y = f2bf(v.y); u.z = f2bf(v.z); u.w = f2bf(v.w);
    *(ushort4*)&img[4 * i] = u;
  }
  if (tid < HW4_ - 6 * SBLK) {  // 6400 - 6144 = 256
    int i = 6 * SBLK + tid;
    float4 v = s4[i];
    ushort4 u;
    u.x = f2bf(v.x); u.y = f2bf(v.y); u.z = f2bf(v.z); u.w = f2bf(v.w);
    *(ushort4*)&img[4 * i] = u;
  }
  __syncthreads();

  const unsigned int* sIdxB = sIdx + (size_t)b * P_;
  const uint2* sWB = sW + (size_t)b * P_;

  if (isPm) {
    unsigned short* dst = pmh + ((size_t)b * QP_ + x) * P_;
    float ssp = 0.f, ssg = 0.f;
    for (int c = 0; c < SBATCH; ++c) {
      int p = c * (4 * SBLK) + tid;
      unsigned iv[4];
      uint2 wv[4];
      float v[4];
#pragma unroll
      for (int j = 0; j < 4; ++j) {
        iv[j] = sIdxB[p + j * SBLK];
        wv[j] = sWB[p + j * SBLK];
      }
#pragma unroll
      for (int j = 0; j < 4; ++j) v[j] = lds_sample(img, iv[j], wv[j]);
#pragma unroll
      for (int j = 0; j < 4; ++j) {
        float pm = v[j];
        float e = __expf(-fabsf(pm));
        float r = __builtin_amdgcn_rcpf(1.f + e);
        float sp = fmaxf(pm, 0.f) - __logf(r);
        float sg = (pm >= 0.f) ? r : e * r;
        ssp += sp;
        ssg += sg;
        dst[p + j * SBLK] = f2bf(pm);
      }
    }
    if (tid < STAIL) {
      int p = SBATCH * 4 * SBLK + tid;
      float pm = lds_sample(img, sIdxB[p], sWB[p]);
      float e = __expf(-fabsf(pm));
      float r = __builtin_amdgcn_rcpf(1.f + e);
      float sp = fmaxf(pm, 0.f) - __logf(r);
      float sg = (pm >= 0.f) ? r : e * r;
      ssp += sp;
      ssg += sg;
      dst[p] = f2bf(pm);
    }
    ssp = waveSum(ssp);
    ssg = waveSum(ssg);
    int w = tid >> 6;
    if ((tid & 63) == 0) {
      red[w] = ssp;
      red[16 + w] = ssg;
    }
    __syncthreads();
    if (tid == 0) {
      float a = 0.f, bb = 0.f;
#pragma unroll
      for (int i = 0; i < 16; ++i) { a += red[i]; bb += red[16 + i]; }
      S_sp[b * Q_ + x] = a;
      S_sig[b * Q_ + x] = bb;
    }
  } else {
    const int t = x - Q_;
    unsigned short* dst = tmh + ((size_t)b * T_ + t) * P_;
    float stm = 0.f;
    for (int c = 0; c < SBATCH; ++c) {
      int p = c * (4 * SBLK) + tid;
      unsigned iv[4];
      uint2 wv[4];
#pragma unroll
      for (int j = 0; j < 4; ++j) {
        iv[j] = sIdxB[p + j * SBLK];
        wv[j] = sWB[p + j * SBLK];
      }
#pragma unroll
      for (int j = 0; j < 4; ++j) {
        float v = lds_sample(img, iv[j], wv[j]);
        stm += v;
        dst[p + j * SBLK] = f2bf(v);
      }
    }
    if (tid < STAIL) {
      int p = SBATCH * 4 * SBLK + tid;
      float v = lds_sample(img, sIdxB[p], sWB[p]);
      stm += v;
      dst[p] = f2bf(v);
    }
    stm = waveSum(stm);
    int w = tid >> 6;
    if ((tid & 63) == 0) red[w] = stm;
    __syncthreads();
    if (tid == 0) {
      float a = 0.f;
#pragma unroll
      for (int i = 0; i < 16; ++i) a += red[i];
      S_tm[b * T_ + t] = a;
    }
  }
}

// convert a pm bf16 A-frag to a sigmoid(pm) bf16 A-frag, elementwise
__device__ __forceinline__ short8 sig_frag(short8 a) {
  short8 out;
#pragma unroll
  for (int j = 0; j < 8; ++j) {
    float x = bf2f((unsigned short)a[j]);
    float e = __expf(-fabsf(x));
    float r = __builtin_amdgcn_rcpf(1.f + e);
    float sg = (x >= 0.f) ? r : e * r;
    out[j] = (short)f2bf(sg);
  }
  return out;
}

// ---------------- phase 3: K-split MFMA GEMM, atomic-free partials.
// Block (seg,b): 5 waves; wave w owns rows 32w..32w+31, both n-tiles,
// both matrices (sig computed in-register from pm frags).
__launch_bounds__(320) __global__
void gemm_kernel(const unsigned short* __restrict__ pmh,
                 const unsigned short* __restrict__ tmh,
                 float* __restrict__ accP) {
  const int b = blockIdx.y;
  const int seg = blockIdx.x;
  const int w = threadIdx.x >> 6;
  const int l = threadIdx.x & 63;
  const int quad = l >> 4;
  const int mrow = l & 15;

  const unsigned short* pmb = pmh + ((size_t)b * QP_ + w * 32) * P_;
  const unsigned short* tmb = tmh + (size_t)b * T_ * P_;

  floatx4 aL[2][2];  // [m-tile local][n-tile]
  floatx4 aS[2][2];
#pragma unroll
  for (int i = 0; i < 2; ++i)
#pragma unroll
    for (int j = 0; j < 2; ++j) {
      aL[i][j] = (floatx4){0.f, 0.f, 0.f, 0.f};
      aS[i][j] = (floatx4){0.f, 0.f, 0.f, 0.f};
    }

  const int kbase = seg * KSEG;
#pragma unroll
  for (int ki = 0; ki < KITER; ++ki) {
    const int k0 = kbase + ki * 32 + quad * 8;
    short8 a0 = *(const short8*)(pmb + (size_t)(0 * 16 + mrow) * P_ + k0);
    short8 a1 = *(const short8*)(pmb + (size_t)(1 * 16 + mrow) * P_ + k0);
    short8 b0 = *(const short8*)(tmb + (size_t)(0 * 16 + mrow) * P_ + k0);
    short8 b1 = *(const short8*)(tmb + (size_t)(1 * 16 + mrow) * P_ + k0);
    short8 s0 = sig_frag(a0);
    short8 s1 = sig_frag(a1);
    aL[0][0] = __builtin_amdgcn_mfma_f32_16x16x32_bf16(a0, b0, aL[0][0], 0, 0, 0);
    aL[0][1] = __builtin_amdgcn_mfma_f32_16x16x32_bf16(a0, b1, aL[0][1], 0, 0, 0);
    aL[1][0] = __builtin_amdgcn_mfma_f32_16x16x32_bf16(a1, b0, aL[1][0], 0, 0, 0);
    aL[1][1] = __builtin_amdgcn_mfma_f32_16x16x32_bf16(a1, b1, aL[1][1], 0, 0, 0);
    aS[0][0] = __builtin_amdgcn_mfma_f32_16x16x32_bf16(s0, b0, aS[0][0], 0, 0, 0);
    aS[0][1] = __builtin_amdgcn_mfma_f32_16x16x32_bf16(s0, b1, aS[0][1], 0, 0, 0);
    aS[1][0] = __builtin_amdgcn_mfma_f32_16x16x32_bf16(s1, b0, aS[1][0], 0, 0, 0);
    aS[1][1] = __builtin_amdgcn_mfma_f32_16x16x32_bf16(s1, b1, aS[1][1], 0, 0, 0);
  }

  // epilogue: plain stores. D layout: row(m)=quad*4+reg, col(n)=lane&15
  float* base = accP + (size_t)seg * DSTRIDE;
#pragma unroll
  for (int mtl = 0; mtl < 2; ++mtl)
#pragma unroll
    for (int nt = 0; nt < 2; ++nt)
#pragma unroll
      for (int r = 0; r < 4; ++r) {
        int q = w * 32 + mtl * 16 + quad * 4 + r;
        int t = nt * 16 + mrow;
        base[((size_t)(0 * B_ + b) * QP_ + q) * T_ + t] = aL[mtl][nt][r];
        base[((size_t)(1 * B_ + b) * QP_ + q) * T_ + t] = aS[mtl][nt][r];
      }
}

// ---------------- phase 3b: reduce partials over segments
__launch_bounds__(256) __global__
void reduce_kernel(const float* __restrict__ accP, float* __restrict__ accD) {
  int i = blockIdx.x * 256 + threadIdx.x;  // < DSTRIDE
  float s = 0.f;
#pragma unroll
  for (int seg = 0; seg < SEG_; ++seg) s += accP[(size_t)seg * DSTRIDE + i];
  accD[i] = s;
}

// ---------------- phase 4: finalize. one wave per (b,q)
__launch_bounds__(64) __global__
void final_kernel(const float* __restrict__ class_q,
                  const int* __restrict__ labels,
                  const float* __restrict__ accD,
                  const float* __restrict__ S_sp,
                  const float* __restrict__ S_sig,
                  const float* __restrict__ S_tm,
                  float* __restrict__ out) {
  const int bq = blockIdx.x;
  const int b = bq / Q_;
  const int q = bq % Q_;
  const int l = threadIdx.x;
  const float* cl = class_q + (size_t)bq * C_;

  float v = -INFINITY;
  for (int c = l; c < C_; c += 64) v = fmaxf(v, cl[c]);
  float m = waveMax(v);
  float e = 0.f;
  for (int c = l; c < C_; c += 64) e += __expf(cl[c] - m);
  float den = waveSum(e);

  if (l < T_) {
    int t = l;
    int lbl = labels[b * T_ + t];
    float prob = __expf(cl[lbl] - m) / den;
    float Dlin = accD[((size_t)(0 * B_ + b) * QP_ + q) * T_ + t];
    float Dsig = accD[((size_t)(1 * B_ + b) * QP_ + q) * T_ + t];
    float cmask = (S_sp[bq] - Dlin) * (1.f / (float)P_);
    float dice = 1.f - (2.f * Dsig + 1.f) / (S_sig[bq] + S_tm[b * T_ + t] + 1.f);
    out[(size_t)bq * T_ + t] = 5.f * cmask + 5.f * dice - prob;
  }
}

extern "C" void kernel_launch(void* const* d_in, const int* in_sizes, int n_in,
                              void* d_out, int out_size, void* d_ws,
                              size_t ws_size, hipStream_t stream) {
  const float* masks_q = (const float*)d_in[0];      // [B,Q,H,W]
  const float* class_q = (const float*)d_in[1];      // [B,Q,C]
  const float* mask_labels = (const float*)d_in[2];  // [B,T,H,W]
  const int* class_labels = (const int*)d_in[3];     // [B,T]
  const float* coords = (const float*)d_in[4];       // [B,P,2]
  float* out = (float*)d_out;

  // ws layout
  float* accD = (float*)d_ws;                         // [2][B][QP_][T_]
  float* accP = accD + DSTRIDE;                       // [SEG_][2][B][QP_][T_]
  uint2* sW = (uint2*)(accP + (size_t)SEG_ * DSTRIDE);  // [B*P] (8B aligned)
  unsigned int* sIdx = (unsigned int*)(sW + (size_t)B_ * P_);  // [B*P]
  float* S_sp = (float*)(sIdx + (size_t)B_ * P_);     // [B*Q]
  float* S_sig = S_sp + B_ * Q_;                      // [B*Q]
  float* S_tm = S_sig + B_ * Q_;                      // [B*T]
  unsigned short* pmh = (unsigned short*)(S_tm + B_ * T_);  // [B][QP_][P]
  unsigned short* tmh = pmh + (size_t)B_ * QP_ * P_;        // [B][T][P]

  samp_kernel<<<(B_ * P_) / 256, 256, 0, stream>>>(coords, sIdx, sW);
  sample_kernel<<<dim3(Q_ + T_, B_), SBLK, 0, stream>>>(
      masks_q, mask_labels, sIdx, sW, pmh, tmh, S_sp, S_sig, S_tm);
  gemm_kernel<<<dim3(SEG_, B_), 320, 0, stream>>>(pmh, tmh, accP);
  reduce_kernel<<<DSTRIDE / 256, 256, 0, stream>>>(accP, accD);
  final_kernel<<<B_ * Q_, 64, 0, stream>>>(class_q, class_labels, accD, S_sp,
                                           S_sig, S_tm, out);
}